// Round 6
// baseline (474.020 us; speedup 1.0000x reference)
//
#include <hip/hip_runtime.h>
#include <hip/hip_bf16.h>
#include <math.h>
#include <stdint.h>

#define BQ 4
#define TQ 12
#define NQ 2000
#define EQ 32000
#define NDQ 16
#define EDQ 8
#define HQ 4
#define DQ 16
#define GQ 64
#define GHQ 64
#define NGQ 48          // B*T graphs
#define LN_EPSQ 1e-5f
#define CCAP 64         // LDS edge cache per node (deg>CCAP falls back to global)
#define ATTN_OFF 520000 // pred(8000) + h_i(512000)

typedef _Float16 half8 __attribute__((ext_vector_type(8)));
typedef float f32x4 __attribute__((ext_vector_type(4)));

// -------------------- CSR build (edge_index shared across graphs) ------------
__global__ void k_count(const int* __restrict__ ei, int* __restrict__ count) {
    int e = blockIdx.x * blockDim.x + threadIdx.x;
    if (e < EQ) atomicAdd(&count[ei[EQ + e]], 1);
}

__global__ void k_scan(const int* __restrict__ count, int* __restrict__ offs,
                       int* __restrict__ cursor) {
    __shared__ int buf[2][2048];
    int t = threadIdx.x;                       // 1024 threads
    for (int i = t; i < 2048; i += 1024)
        buf[0][i] = (i < NQ) ? count[i] : 0;
    __syncthreads();
    int src = 0;
    for (int sh = 1; sh < 2048; sh <<= 1) {
        int dst = src ^ 1;
        for (int i = t; i < 2048; i += 1024) {
            int v = buf[src][i];
            if (i >= sh) v += buf[src][i - sh];
            buf[dst][i] = v;
        }
        __syncthreads();
        src = dst;
    }
    for (int i = t; i <= NQ; i += 1024) {
        int off = (i == 0) ? 0 : buf[src][i - 1];
        offs[i] = off;
        if (i < NQ) cursor[i] = off;
    }
}

__global__ void k_scatter(const int* __restrict__ ei, int* __restrict__ cursor,
                          int2* __restrict__ csr2) {
    int e = blockIdx.x * blockDim.x + threadIdx.x;
    if (e < EQ) {
        int pos = atomicAdd(&cursor[ei[EQ + e]], 1);
        csr2[pos] = make_int2(e, ei[e]);       // (eid, src)
    }
}

// -------------------- node projection: one THREAD per (g,n) ------------------
__global__ void __launch_bounds__(256) k_nodeproj(
        const float* __restrict__ xf, const float* __restrict__ Wn,
        const float* __restrict__ att,
        _Float16* __restrict__ hprojH, float* __restrict__ sd,
        float* __restrict__ ss) {
    __shared__ __align__(16) float4 Wl4[NDQ * 16];   // [i][j4] row-major, 4KB
    __shared__ float attl[HQ * 48];
    int t = threadIdx.x;
    for (int i = t; i < NDQ * 16; i += 256) Wl4[i] = ((const float4*)Wn)[i];
    if (t < HQ * 48) attl[t] = att[t];
    __syncthreads();
    int id = blockIdx.x * 256 + t;                   // g*NQ + n, total 96000
    const float4* xp = (const float4*)(xf + (size_t)id * NDQ);
    float4 xv0 = xp[0], xv1 = xp[1], xv2 = xp[2], xv3 = xp[3];
    float xr[16] = {xv0.x, xv0.y, xv0.z, xv0.w, xv1.x, xv1.y, xv1.z, xv1.w,
                    xv2.x, xv2.y, xv2.z, xv2.w, xv3.x, xv3.y, xv3.z, xv3.w};
    float acc[64];
#pragma unroll
    for (int j = 0; j < 64; ++j) acc[j] = 0.f;
#pragma unroll
    for (int i = 0; i < 16; ++i) {
        float xi = xr[i];
#pragma unroll
        for (int j4 = 0; j4 < 16; ++j4) {
            float4 wv = Wl4[i * 16 + j4];            // uniform addr: broadcast
            acc[j4 * 4 + 0] = fmaf(xi, wv.x, acc[j4 * 4 + 0]);
            acc[j4 * 4 + 1] = fmaf(xi, wv.y, acc[j4 * 4 + 1]);
            acc[j4 * 4 + 2] = fmaf(xi, wv.z, acc[j4 * 4 + 2]);
            acc[j4 * 4 + 3] = fmaf(xi, wv.w, acc[j4 * 4 + 3]);
        }
    }
    float sdv[4], ssv[4];
#pragma unroll
    for (int hh = 0; hh < 4; ++hh) {
        float vd = 0.f, vs = 0.f;
#pragma unroll
        for (int d = 0; d < 16; ++d) {
            vd = fmaf(acc[hh * 16 + d], attl[hh * 48 + d], vd);
            vs = fmaf(acc[hh * 16 + d], attl[hh * 48 + 16 + d], vs);
        }
        sdv[hh] = vd; ssv[hh] = vs;
    }
    *(float4*)&sd[(size_t)id * 4] = make_float4(sdv[0], sdv[1], sdv[2], sdv[3]);
    *(float4*)&ss[(size_t)id * 4] = make_float4(ssv[0], ssv[1], ssv[2], ssv[3]);
#pragma unroll
    for (int p = 0; p < 8; ++p) {
        half8 hv;
#pragma unroll
        for (int i = 0; i < 8; ++i) hv[i] = (_Float16)acc[p * 8 + i];
        *(half8*)&hprojH[(size_t)id * GQ + p * 8] = hv;
    }
}

// ------ fused: edge-score + softmax + aggregate + ELU + LN (wave per node) ---
// pass 1: lane = edge (global loads once, cache to LDS, head-max reduce)
// pass 2: lane = (h, c) over LDS; pass 3: lane = edge (atomic attn accumulate)
// phase B: lane = output feature j
__global__ void __launch_bounds__(256) k_fused(
        const float* __restrict__ ef, const float* __restrict__ We,
        const float* __restrict__ att,
        const int* __restrict__ offs, const int2* __restrict__ csr2,
        const float* __restrict__ sd, const float* __restrict__ ss,
        const _Float16* __restrict__ hprojH,
        const float* __restrict__ gamma, const float* __restrict__ beta,
        float* __restrict__ outAttn, _Float16* __restrict__ spatialH) {
    __shared__ float Wl[EDQ * GQ];                       // 2KB: We staged
    __shared__ __align__(16) float WA[EDQ * HQ];         // [i][h] factored edge-attn
    __shared__ __align__(16) float ecache[4][CCAP * 4];  // 4KB: score->exp per (edge,h)
    __shared__ half8 eac[4][CCAP];                       // 4KB: ea as f16x8
    __shared__ int   srcs[4][CCAP];                      // 1KB
    __shared__ int   eids[4][CCAP];                      // 1KB
    int t = threadIdx.x;
    for (int i = t; i < EDQ * GQ; i += 256) Wl[i] = We[i];
    if (t < EDQ * HQ) {
        int i = t >> 2, h4 = t & 3;
        float s = 0.f;
#pragma unroll
        for (int d = 0; d < DQ; ++d)
            s = fmaf(We[i * GQ + h4 * DQ + d], att[h4 * 48 + 32 + d], s);
        WA[t] = s;
    }
    __syncthreads();
    int w = t >> 6, lane = t & 63;
    int wid = blockIdx.x * 4 + w;              // exact: grid = NGQ*NQ/4
    int g = wid / NQ, n = wid % NQ;
    int beg = offs[n], deg = offs[n + 1] - beg;
    size_t ebase = (size_t)g * EQ;
    size_t nbase = (size_t)g * NQ;
    float4 sd4 = *(const float4*)&sd[(nbase + n) * HQ];
    // ---- pass 1 (edge-parallel): load once, score all heads, cache ---------
    float mxr[4] = {-1e30f, -1e30f, -1e30f, -1e30f};
    for (int k = lane; k < deg; k += 64) {
        int2 pr = csr2[beg + k];
        float4 ssv = *(const float4*)&ss[(nbase + pr.y) * HQ];
        const float4* eap = (const float4*)(ef + (ebase + pr.x) * EDQ);
        float4 lo = eap[0], hi = eap[1];
        float scv[4];
#pragma unroll
        for (int hh = 0; hh < 4; ++hh) {
            float se =      lo.x * WA[0 * 4 + hh];
            se = fmaf(lo.y, WA[1 * 4 + hh], se); se = fmaf(lo.z, WA[2 * 4 + hh], se);
            se = fmaf(lo.w, WA[3 * 4 + hh], se); se = fmaf(hi.x, WA[4 * 4 + hh], se);
            se = fmaf(hi.y, WA[5 * 4 + hh], se); se = fmaf(hi.z, WA[6 * 4 + hh], se);
            se = fmaf(hi.w, WA[7 * 4 + hh], se);
            float sdh = (hh == 0) ? sd4.x : (hh == 1) ? sd4.y : (hh == 2) ? sd4.z : sd4.w;
            float ssh = (hh == 0) ? ssv.x : (hh == 1) ? ssv.y : (hh == 2) ? ssv.z : ssv.w;
            float sc = sdh + ssh + se;
            sc = (sc >= 0.f) ? sc : 0.2f * sc;
            scv[hh] = sc;
            mxr[hh] = fmaxf(mxr[hh], sc);
        }
        if (k < CCAP) {
            *(float4*)&ecache[w][k * 4] = make_float4(scv[0], scv[1], scv[2], scv[3]);
            half8 hv;
            hv[0] = (_Float16)lo.x; hv[1] = (_Float16)lo.y;
            hv[2] = (_Float16)lo.z; hv[3] = (_Float16)lo.w;
            hv[4] = (_Float16)hi.x; hv[5] = (_Float16)hi.y;
            hv[6] = (_Float16)hi.z; hv[7] = (_Float16)hi.w;
            eac[w][k] = hv;
            srcs[w][k] = pr.y;
            eids[w][k] = pr.x;
        }
    }
#pragma unroll
    for (int s = 1; s < 64; s <<= 1) {
#pragma unroll
        for (int hh = 0; hh < 4; ++hh)
            mxr[hh] = fmaxf(mxr[hh], __shfl_xor(mxr[hh], s, 64));
    }
    int h = lane >> 4, c = lane & 15;
    float mxh = (h == 0) ? mxr[0] : (h == 1) ? mxr[1] : (h == 2) ? mxr[2] : mxr[3];
    float sdh = (h == 0) ? sd4.x : (h == 1) ? sd4.y : (h == 2) ? sd4.z : sd4.w;
    // ---- pass 2 (LDS): exp, sum, weighted edge-feature sums ----------------
    float sum = 0.f;
    float ws[8] = {0.f, 0.f, 0.f, 0.f, 0.f, 0.f, 0.f, 0.f};
    for (int k = c; k < deg; k += 16) {
        float e;
        if (k < CCAP) {
            e = __expf(ecache[w][k * 4 + h] - mxh);
            ecache[w][k * 4 + h] = e;
            half8 ev = eac[w][k];
#pragma unroll
            for (int i = 0; i < 8; ++i) ws[i] = fmaf(e, (float)ev[i], ws[i]);
        } else {                               // cold: deg > CCAP
            int2 pr = csr2[beg + k];
            float4 ssv = *(const float4*)&ss[(nbase + pr.y) * HQ];
            float ssh = (h == 0) ? ssv.x : (h == 1) ? ssv.y : (h == 2) ? ssv.z : ssv.w;
            const float4* eap = (const float4*)(ef + (ebase + pr.x) * EDQ);
            float4 lo = eap[0], hi = eap[1];
            float se =      lo.x * WA[0 * 4 + h];
            se = fmaf(lo.y, WA[1 * 4 + h], se); se = fmaf(lo.z, WA[2 * 4 + h], se);
            se = fmaf(lo.w, WA[3 * 4 + h], se); se = fmaf(hi.x, WA[4 * 4 + h], se);
            se = fmaf(hi.y, WA[5 * 4 + h], se); se = fmaf(hi.z, WA[6 * 4 + h], se);
            se = fmaf(hi.w, WA[7 * 4 + h], se);
            float sc = sdh + ssh + se;
            sc = (sc >= 0.f) ? sc : 0.2f * sc;
            e = __expf(sc - mxh);
            ws[0] = fmaf(e, lo.x, ws[0]); ws[1] = fmaf(e, lo.y, ws[1]);
            ws[2] = fmaf(e, lo.z, ws[2]); ws[3] = fmaf(e, lo.w, ws[3]);
            ws[4] = fmaf(e, hi.x, ws[4]); ws[5] = fmaf(e, hi.y, ws[5]);
            ws[6] = fmaf(e, hi.z, ws[6]); ws[7] = fmaf(e, hi.w, ws[7]);
        }
        sum += e;
    }
#pragma unroll
    for (int s = 1; s < 16; s <<= 1) {
        sum += __shfl_xor(sum, s, 16);
#pragma unroll
        for (int i = 0; i < 8; ++i) ws[i] += __shfl_xor(ws[i], s, 16);
    }
    float inv = 1.f / (sum + 1e-16f);
#pragma unroll
    for (int i = 0; i < 8; ++i) ws[i] *= inv;
    // ---- pass 3 (edge-parallel): atomic attn-mean accumulate ---------------
    float inv4[4];
#pragma unroll
    for (int hh = 0; hh < 4; ++hh) inv4[hh] = __shfl(inv, hh * 16, 64);
    int tt = g % TQ;
    float* aout = outAttn + ATTN_OFF + (size_t)tt * EQ * HQ;
    for (int k = lane; k < deg; k += 64) {
        float e4[4]; int eid;
        if (k < CCAP) {
            eid = eids[w][k];
            float4 ev = *(const float4*)&ecache[w][k * 4];
            e4[0] = ev.x; e4[1] = ev.y; e4[2] = ev.z; e4[3] = ev.w;
        } else {
            int2 pr = csr2[beg + k];
            eid = pr.x;
            float4 ssv = *(const float4*)&ss[(nbase + pr.y) * HQ];
            const float4* eap = (const float4*)(ef + (ebase + pr.x) * EDQ);
            float4 lo = eap[0], hi = eap[1];
#pragma unroll
            for (int hh = 0; hh < 4; ++hh) {
                float se =      lo.x * WA[0 * 4 + hh];
                se = fmaf(lo.y, WA[1 * 4 + hh], se); se = fmaf(lo.z, WA[2 * 4 + hh], se);
                se = fmaf(lo.w, WA[3 * 4 + hh], se); se = fmaf(hi.x, WA[4 * 4 + hh], se);
                se = fmaf(hi.y, WA[5 * 4 + hh], se); se = fmaf(hi.z, WA[6 * 4 + hh], se);
                se = fmaf(hi.w, WA[7 * 4 + hh], se);
                float sdh2 = (hh == 0) ? sd4.x : (hh == 1) ? sd4.y : (hh == 2) ? sd4.z : sd4.w;
                float ssh2 = (hh == 0) ? ssv.x : (hh == 1) ? ssv.y : (hh == 2) ? ssv.z : ssv.w;
                float sc = sdh2 + ssh2 + se;
                sc = (sc >= 0.f) ? sc : 0.2f * sc;
                e4[hh] = __expf(sc - mxr[hh]);
            }
        }
#pragma unroll
        for (int hh = 0; hh < 4; ++hh)
            atomicAdd(&aout[(size_t)eid * HQ + hh], 0.25f * e4[hh] * inv4[hh]);
    }
    // ---- phase B: aggregate alpha*h[src] (f16 gathers), ELU + LN -----------
    int dmain = deg < CCAP ? deg : CCAP;
    const _Float16* hp = hprojH + nbase * GQ + lane;
    float acc = 0.f;
    int k = 0;
    for (; k + 8 <= dmain; k += 8) {
        float e0 = ecache[w][(k + 0) * 4 + h], e1 = ecache[w][(k + 1) * 4 + h];
        float e2 = ecache[w][(k + 2) * 4 + h], e3 = ecache[w][(k + 3) * 4 + h];
        float e4 = ecache[w][(k + 4) * 4 + h], e5 = ecache[w][(k + 5) * 4 + h];
        float e6 = ecache[w][(k + 6) * 4 + h], e7 = ecache[w][(k + 7) * 4 + h];
        float h0 = (float)hp[(size_t)srcs[w][k + 0] * GQ];
        float h1 = (float)hp[(size_t)srcs[w][k + 1] * GQ];
        float h2 = (float)hp[(size_t)srcs[w][k + 2] * GQ];
        float h3 = (float)hp[(size_t)srcs[w][k + 3] * GQ];
        float h4 = (float)hp[(size_t)srcs[w][k + 4] * GQ];
        float h5 = (float)hp[(size_t)srcs[w][k + 5] * GQ];
        float h6 = (float)hp[(size_t)srcs[w][k + 6] * GQ];
        float h7 = (float)hp[(size_t)srcs[w][k + 7] * GQ];
        acc = fmaf(e0, h0, acc); acc = fmaf(e1, h1, acc);
        acc = fmaf(e2, h2, acc); acc = fmaf(e3, h3, acc);
        acc = fmaf(e4, h4, acc); acc = fmaf(e5, h5, acc);
        acc = fmaf(e6, h6, acc); acc = fmaf(e7, h7, acc);
    }
    for (; k < dmain; ++k) {
        float e0 = ecache[w][k * 4 + h];
        float h0 = (float)hp[(size_t)srcs[w][k] * GQ];
        acc = fmaf(e0, h0, acc);
    }
    for (; k < deg; ++k) {                     // cold path
        int2 pr = csr2[beg + k];
        float4 ssv = *(const float4*)&ss[(nbase + pr.y) * HQ];
        float ssh = (h == 0) ? ssv.x : (h == 1) ? ssv.y : (h == 2) ? ssv.z : ssv.w;
        const float4* eap = (const float4*)(ef + (ebase + pr.x) * EDQ);
        float4 lo = eap[0], hi = eap[1];
        float se =      lo.x * WA[0 * 4 + h];
        se = fmaf(lo.y, WA[1 * 4 + h], se); se = fmaf(lo.z, WA[2 * 4 + h], se);
        se = fmaf(lo.w, WA[3 * 4 + h], se); se = fmaf(hi.x, WA[4 * 4 + h], se);
        se = fmaf(hi.y, WA[5 * 4 + h], se); se = fmaf(hi.z, WA[6 * 4 + h], se);
        se = fmaf(hi.w, WA[7 * 4 + h], se);
        float sc = sdh + ssh + se;
        sc = (sc >= 0.f) ? sc : 0.2f * sc;
        float e0 = __expf(sc - mxh);
        float h0 = (float)hp[(size_t)pr.y * GQ];
        acc = fmaf(e0, h0, acc);
    }
    acc *= inv;
    float t2 = 0.f;
#pragma unroll
    for (int i = 0; i < 8; ++i) t2 = fmaf(ws[i], Wl[i * GQ + lane], t2);
    float x = acc + t2;
    x = (x > 0.f) ? x : (__expf(x) - 1.f);     // ELU
    float s1 = x, s2v = x * x;
#pragma unroll
    for (int s = 32; s >= 1; s >>= 1) {
        s1 += __shfl_xor(s1, s, 64);
        s2v += __shfl_xor(s2v, s, 64);
    }
    float mu = s1 * (1.f / 64.f);
    float var = s2v * (1.f / 64.f) - mu * mu;
    float y = (x - mu) * rsqrtf(var + LN_EPSQ) * gamma[lane] + beta[lane];
    spatialH[(nbase + n) * GQ + lane] = (_Float16)y;
}

// -------------------- GRU via MFMA (f16 inputs, f32 accum) -------------------
// block = 16 sequences, 4 waves; wave w owns hidden cols [16w,16w+16)
// A-frag: lane l -> A[l%16][8*(l/16)+i]; C-frag: row=(l/16)*4+reg, col=l%16
__device__ inline f32x4 MF(half8 a, half8 b, f32x4 c) {
    return __builtin_amdgcn_mfma_f32_16x16x32_f16(a, b, c, 0, 0, 0);
}

__global__ void __launch_bounds__(256) k_gru(
        const _Float16* __restrict__ xh,     // [48][2000][64] f16 (g = b*12+t)
        const float* __restrict__ Wih, const float* __restrict__ Whh,
        const float* __restrict__ bih, const float* __restrict__ bhh,
        const float* __restrict__ Wout, const float* __restrict__ bout,
        float* __restrict__ out) {
    __shared__ _Float16 hlds[16][72];          // +8 pad: 144B row stride
    __shared__ float pred_s[4][16];
    int tid = threadIdx.x;
    int w = tid >> 6, l = tid & 63;
    int lr = l & 15, lg = l >> 4;
    int j = w * 16 + lr;                       // this lane's hidden/gate column
    half8 wiF[3][2], whF[3][2];
#pragma unroll
    for (int gb = 0; gb < 3; ++gb) {
        int q = gb * 64 + j;
#pragma unroll
        for (int kt = 0; kt < 2; ++kt) {
            const float* p  = Wih + q * 64 + kt * 32 + lg * 8;
            const float* p2 = Whh + q * 64 + kt * 32 + lg * 8;
            half8 a, b;
#pragma unroll
            for (int i = 0; i < 8; ++i) { a[i] = (_Float16)p[i]; b[i] = (_Float16)p2[i]; }
            wiF[gb][kt] = a; whF[gb][kt] = b;
        }
    }
    float br  = bih[j] + bhh[j];
    float bz  = bih[64 + j] + bhh[64 + j];
    float bin = bih[128 + j];
    float bhn = bhh[128 + j];
    float wo  = Wout[j];
    for (int i = tid; i < 16 * 72; i += 256) ((_Float16*)hlds)[i] = (_Float16)0.f;
    int id0 = blockIdx.x * 16;
    const _Float16* xp0;
    {
        int id = id0 + lr;
        int b = id / NQ, n = id - b * NQ;
        xp0 = xh + ((size_t)b * TQ * NQ + n) * GQ + lg * 8;
    }
    half8 xa[2];
    xa[0] = *(const half8*)xp0; xa[1] = *(const half8*)(xp0 + 32);
    float hprev[4] = {0.f, 0.f, 0.f, 0.f};
    __syncthreads();
    for (int t = 0; t < TQ; ++t) {
        f32x4 aR  = (f32x4){br, br, br, br};
        f32x4 aZ  = (f32x4){bz, bz, bz, bz};
        f32x4 aIN = (f32x4){bin, bin, bin, bin};
        f32x4 aHN = (f32x4){bhn, bhn, bhn, bhn};
#pragma unroll
        for (int kt = 0; kt < 2; ++kt) {
            aR  = MF(xa[kt], wiF[0][kt], aR);
            aZ  = MF(xa[kt], wiF[1][kt], aZ);
            aIN = MF(xa[kt], wiF[2][kt], aIN);
        }
        half8 ha[2];
        ha[0] = *(const half8*)&hlds[lr][lg * 8];
        ha[1] = *(const half8*)&hlds[lr][32 + lg * 8];
#pragma unroll
        for (int kt = 0; kt < 2; ++kt) {
            aR  = MF(ha[kt], whF[0][kt], aR);
            aZ  = MF(ha[kt], whF[1][kt], aZ);
            aHN = MF(ha[kt], whF[2][kt], aHN);
        }
        if (t + 1 < TQ) {
            xp0 += (size_t)NQ * GQ;
            xa[0] = *(const half8*)xp0; xa[1] = *(const half8*)(xp0 + 32);
        }
#pragma unroll
        for (int r4 = 0; r4 < 4; ++r4) {
            float r = 1.f / (1.f + __expf(-aR[r4]));
            float z = 1.f / (1.f + __expf(-aZ[r4]));
            float xg = aIN[r4] + r * aHN[r4];
            float e2 = __expf(2.f * xg);
            float nn = 1.f - 2.f / (e2 + 1.f);     // tanh(xg)
            hprev[r4] = z * (hprev[r4] - nn) + nn;
        }
        __syncthreads();
#pragma unroll
        for (int r4 = 0; r4 < 4; ++r4)
            hlds[4 * lg + r4][j] = (_Float16)hprev[r4];
        __syncthreads();
    }
    float pv[4];
#pragma unroll
    for (int r4 = 0; r4 < 4; ++r4) {
        int id = id0 + 4 * lg + r4;
        out[8000 + (size_t)id * GHQ + j] = hprev[r4];
        pv[r4] = hprev[r4] * wo;
    }
#pragma unroll
    for (int s = 1; s <= 8; s <<= 1)
#pragma unroll
        for (int r4 = 0; r4 < 4; ++r4)
            pv[r4] += __shfl_xor(pv[r4], s);
    if (lr == 0) {
#pragma unroll
        for (int r4 = 0; r4 < 4; ++r4)
            pred_s[w][4 * lg + r4] = pv[r4];
    }
    __syncthreads();
    if (tid < 16) {
        float s = pred_s[0][tid] + pred_s[1][tid] + pred_s[2][tid] + pred_s[3][tid] + bout[0];
        out[id0 + tid] = s;
    }
}

extern "C" void kernel_launch(void* const* d_in, const int* in_sizes, int n_in,
                              void* d_out, int out_size, void* d_ws, size_t ws_size,
                              hipStream_t stream) {
    const float* nodef = (const float*)d_in[0];
    const float* edgef = (const float*)d_in[1];
    const float* Wn    = (const float*)d_in[2];
    const float* We    = (const float*)d_in[3];
    const float* att   = (const float*)d_in[4];
    const float* gamma = (const float*)d_in[5];
    const float* beta  = (const float*)d_in[6];
    const float* Wih   = (const float*)d_in[7];
    const float* Whh   = (const float*)d_in[8];
    const float* bih   = (const float*)d_in[9];
    const float* bhh   = (const float*)d_in[10];
    const float* Wout  = (const float*)d_in[11];
    const float* bout  = (const float*)d_in[12];
    const int*   ei    = (const int*)d_in[13];

    char* ws = (char*)d_ws;
    size_t o = 0;
    int*  count  = (int*)(ws + o);  o += 2048 * 4;
    int*  offs   = (int*)(ws + o);  o += 2048 * 4;
    int*  cursor = (int*)(ws + o);  o += 2048 * 4;
    int2* csr2   = (int2*)(ws + o); o += (size_t)EQ * 8;
    float* sd      = (float*)(ws + o); o += (size_t)NGQ * NQ * HQ * 4;
    float* ss      = (float*)(ws + o); o += (size_t)NGQ * NQ * HQ * 4;
    _Float16* hprojH   = (_Float16*)(ws + o); o += (size_t)NGQ * NQ * GQ * 2;
    _Float16* spatialH = (_Float16*)(ws + o); o += (size_t)NGQ * NQ * GQ * 2;

    hipMemsetAsync(count, 0, NQ * sizeof(int), stream);
    hipMemsetAsync((float*)d_out + ATTN_OFF, 0, (size_t)TQ * EQ * HQ * 4, stream);
    k_count  <<<(EQ + 255) / 256, 256, 0, stream>>>(ei, count);
    k_scan   <<<1, 1024, 0, stream>>>(count, offs, cursor);
    k_scatter<<<(EQ + 255) / 256, 256, 0, stream>>>(ei, cursor, csr2);

    k_nodeproj<<<(NGQ * NQ) / 256, 256, 0, stream>>>(nodef, Wn, att, hprojH, sd, ss);
    k_fused   <<<(NGQ * NQ) / 4, 256, 0, stream>>>(edgef, We, att, offs, csr2,
                                                   sd, ss, hprojH, gamma, beta,
                                                   (float*)d_out, spatialH);
    k_gru     <<<(BQ * NQ) / 16, 256, 0, stream>>>(spatialH, Wih, Whh, bih, bhh,
                                                   Wout, bout, (float*)d_out);
}

// Round 7
// 391.627 us; speedup vs baseline: 1.2104x; 1.2104x over previous
//
#include <hip/hip_runtime.h>
#include <hip/hip_bf16.h>
#include <math.h>
#include <stdint.h>

#define BQ 4
#define TQ 12
#define NQ 2000
#define EQ 32000
#define NDQ 16
#define EDQ 8
#define HQ 4
#define DQ 16
#define GQ 64
#define GHQ 64
#define NGQ 48          // B*T graphs
#define LN_EPSQ 1e-5f
#define CCAP 64         // LDS edge cache per node (deg>CCAP falls back to global)
#define PF 16           // register-prefetched gathers per node
#define ATTN_OFF 520000 // pred(8000) + h_i(512000)

typedef _Float16 half8 __attribute__((ext_vector_type(8)));
typedef _Float16 half4v __attribute__((ext_vector_type(4)));
typedef float f32x4 __attribute__((ext_vector_type(4)));

// -------------------- CSR build (edge_index shared across graphs) ------------
__global__ void k_count(const int* __restrict__ ei, int* __restrict__ count) {
    int e = blockIdx.x * blockDim.x + threadIdx.x;
    if (e < EQ) atomicAdd(&count[ei[EQ + e]], 1);
}

__global__ void k_scan(const int* __restrict__ count, int* __restrict__ offs,
                       int* __restrict__ cursor) {
    __shared__ int buf[2][2048];
    int t = threadIdx.x;                       // 1024 threads
    for (int i = t; i < 2048; i += 1024)
        buf[0][i] = (i < NQ) ? count[i] : 0;
    __syncthreads();
    int src = 0;
    for (int sh = 1; sh < 2048; sh <<= 1) {
        int dst = src ^ 1;
        for (int i = t; i < 2048; i += 1024) {
            int v = buf[src][i];
            if (i >= sh) v += buf[src][i - sh];
            buf[dst][i] = v;
        }
        __syncthreads();
        src = dst;
    }
    for (int i = t; i <= NQ; i += 1024) {
        int off = (i == 0) ? 0 : buf[src][i - 1];
        offs[i] = off;
        if (i < NQ) cursor[i] = off;
    }
}

__global__ void k_scatter(const int* __restrict__ ei, int* __restrict__ cursor,
                          int2* __restrict__ csr2) {
    int e = blockIdx.x * blockDim.x + threadIdx.x;
    if (e < EQ) {
        int pos = atomicAdd(&cursor[ei[EQ + e]], 1);
        csr2[pos] = make_int2(e, ei[e]);       // (eid, src)
    }
}

// -------------------- node projection: one THREAD per (g,n) ------------------
__global__ void __launch_bounds__(256) k_nodeproj(
        const float* __restrict__ xf, const float* __restrict__ Wn,
        const float* __restrict__ att,
        _Float16* __restrict__ hprojH, float* __restrict__ sd,
        float* __restrict__ ss) {
    __shared__ __align__(16) float4 Wl4[NDQ * 16];   // [i][j4] row-major, 4KB
    __shared__ float attl[HQ * 48];
    int t = threadIdx.x;
    for (int i = t; i < NDQ * 16; i += 256) Wl4[i] = ((const float4*)Wn)[i];
    if (t < HQ * 48) attl[t] = att[t];
    __syncthreads();
    int id = blockIdx.x * 256 + t;                   // g*NQ + n, total 96000
    const float4* xp = (const float4*)(xf + (size_t)id * NDQ);
    float4 xv0 = xp[0], xv1 = xp[1], xv2 = xp[2], xv3 = xp[3];
    float xr[16] = {xv0.x, xv0.y, xv0.z, xv0.w, xv1.x, xv1.y, xv1.z, xv1.w,
                    xv2.x, xv2.y, xv2.z, xv2.w, xv3.x, xv3.y, xv3.z, xv3.w};
    float acc[64];
#pragma unroll
    for (int j = 0; j < 64; ++j) acc[j] = 0.f;
#pragma unroll
    for (int i = 0; i < 16; ++i) {
        float xi = xr[i];
#pragma unroll
        for (int j4 = 0; j4 < 16; ++j4) {
            float4 wv = Wl4[i * 16 + j4];            // uniform addr: broadcast
            acc[j4 * 4 + 0] = fmaf(xi, wv.x, acc[j4 * 4 + 0]);
            acc[j4 * 4 + 1] = fmaf(xi, wv.y, acc[j4 * 4 + 1]);
            acc[j4 * 4 + 2] = fmaf(xi, wv.z, acc[j4 * 4 + 2]);
            acc[j4 * 4 + 3] = fmaf(xi, wv.w, acc[j4 * 4 + 3]);
        }
    }
    float sdv[4], ssv[4];
#pragma unroll
    for (int hh = 0; hh < 4; ++hh) {
        float vd = 0.f, vs = 0.f;
#pragma unroll
        for (int d = 0; d < 16; ++d) {
            vd = fmaf(acc[hh * 16 + d], attl[hh * 48 + d], vd);
            vs = fmaf(acc[hh * 16 + d], attl[hh * 48 + 16 + d], vs);
        }
        sdv[hh] = vd; ssv[hh] = vs;
    }
    *(float4*)&sd[(size_t)id * 4] = make_float4(sdv[0], sdv[1], sdv[2], sdv[3]);
    *(float4*)&ss[(size_t)id * 4] = make_float4(ssv[0], ssv[1], ssv[2], ssv[3]);
#pragma unroll
    for (int p = 0; p < 8; ++p) {
        half8 hv;
#pragma unroll
        for (int i = 0; i < 8; ++i) hv[i] = (_Float16)acc[p * 8 + i];
        *(half8*)&hprojH[(size_t)id * GQ + p * 8] = hv;
    }
}

// ------ fused: edge-score + softmax + aggregate + ELU + LN (wave per node) ---
// pass 1: lane = edge (global loads once, cache to LDS, head-max reduce)
// prefetch: lane = feature (first PF hproj gathers into regs, hides latency)
// pass 2: lane = (h, c) over LDS; pass 3: lane = edge (half4 alpha store)
// phase B: lane = output feature j
__global__ void __launch_bounds__(256) k_fused(
        const float* __restrict__ ef, const float* __restrict__ We,
        const float* __restrict__ att,
        const int* __restrict__ offs, const int2* __restrict__ csr2,
        const float* __restrict__ sd, const float* __restrict__ ss,
        const _Float16* __restrict__ hprojH,
        const float* __restrict__ gamma, const float* __restrict__ beta,
        _Float16* __restrict__ alphaH, _Float16* __restrict__ spatialH) {
    __shared__ float Wl[EDQ * GQ];                       // 2KB: We staged
    __shared__ __align__(16) float WA[EDQ * HQ];         // [i][h] factored edge-attn
    __shared__ __align__(16) float ecache[4][CCAP * 4];  // 4KB: score->exp per (edge,h)
    __shared__ half8 eac[4][CCAP];                       // 4KB: ea as f16x8
    __shared__ int   srcs[4][CCAP];                      // 1KB
    __shared__ int   eids[4][CCAP];                      // 1KB
    int t = threadIdx.x;
    for (int i = t; i < EDQ * GQ; i += 256) Wl[i] = We[i];
    if (t < EDQ * HQ) {
        int i = t >> 2, h4 = t & 3;
        float s = 0.f;
#pragma unroll
        for (int d = 0; d < DQ; ++d)
            s = fmaf(We[i * GQ + h4 * DQ + d], att[h4 * 48 + 32 + d], s);
        WA[t] = s;
    }
    __syncthreads();
    int w = t >> 6, lane = t & 63;
    int wid = blockIdx.x * 4 + w;              // exact: grid = NGQ*NQ/4
    int g = wid / NQ, n = wid % NQ;
    int beg = offs[n], deg = offs[n + 1] - beg;
    size_t ebase = (size_t)g * EQ;
    size_t nbase = (size_t)g * NQ;
    float4 sd4 = *(const float4*)&sd[(nbase + n) * HQ];
    // ---- pass 1 (edge-parallel): load once, score all heads, cache ---------
    float mxr[4] = {-1e30f, -1e30f, -1e30f, -1e30f};
    for (int k = lane; k < deg; k += 64) {
        int2 pr = csr2[beg + k];
        float4 ssv = *(const float4*)&ss[(nbase + pr.y) * HQ];
        const float4* eap = (const float4*)(ef + (ebase + pr.x) * EDQ);
        float4 lo = eap[0], hi = eap[1];
        float scv[4];
#pragma unroll
        for (int hh = 0; hh < 4; ++hh) {
            float se =      lo.x * WA[0 * 4 + hh];
            se = fmaf(lo.y, WA[1 * 4 + hh], se); se = fmaf(lo.z, WA[2 * 4 + hh], se);
            se = fmaf(lo.w, WA[3 * 4 + hh], se); se = fmaf(hi.x, WA[4 * 4 + hh], se);
            se = fmaf(hi.y, WA[5 * 4 + hh], se); se = fmaf(hi.z, WA[6 * 4 + hh], se);
            se = fmaf(hi.w, WA[7 * 4 + hh], se);
            float sdh = (hh == 0) ? sd4.x : (hh == 1) ? sd4.y : (hh == 2) ? sd4.z : sd4.w;
            float ssh = (hh == 0) ? ssv.x : (hh == 1) ? ssv.y : (hh == 2) ? ssv.z : ssv.w;
            float sc = sdh + ssh + se;
            sc = (sc >= 0.f) ? sc : 0.2f * sc;
            scv[hh] = sc;
            mxr[hh] = fmaxf(mxr[hh], sc);
        }
        if (k < CCAP) {
            *(float4*)&ecache[w][k * 4] = make_float4(scv[0], scv[1], scv[2], scv[3]);
            half8 hv;
            hv[0] = (_Float16)lo.x; hv[1] = (_Float16)lo.y;
            hv[2] = (_Float16)lo.z; hv[3] = (_Float16)lo.w;
            hv[4] = (_Float16)hi.x; hv[5] = (_Float16)hi.y;
            hv[6] = (_Float16)hi.z; hv[7] = (_Float16)hi.w;
            eac[w][k] = hv;
            srcs[w][k] = pr.y;
            eids[w][k] = pr.x;
        }
    }
#pragma unroll
    for (int s = 1; s < 64; s <<= 1) {
#pragma unroll
        for (int hh = 0; hh < 4; ++hh)
            mxr[hh] = fmaxf(mxr[hh], __shfl_xor(mxr[hh], s, 64));
    }
    // ---- register prefetch of first PF hproj gathers (overlaps pass 2) -----
    int dmain = deg < CCAP ? deg : CCAP;
    const _Float16* hp = hprojH + nbase * GQ + lane;   // lane = feature here
    int dpf = (dmain < PF) ? dmain : PF;
    _Float16 hpre[PF];
#pragma unroll
    for (int k = 0; k < PF; ++k)
        if (k < dpf) hpre[k] = hp[(size_t)srcs[w][k] * GQ];
    int h = lane >> 4, c = lane & 15;
    float mxh = (h == 0) ? mxr[0] : (h == 1) ? mxr[1] : (h == 2) ? mxr[2] : mxr[3];
    float sdh = (h == 0) ? sd4.x : (h == 1) ? sd4.y : (h == 2) ? sd4.z : sd4.w;
    // ---- pass 2 (LDS): exp, sum, weighted edge-feature sums ----------------
    float sum = 0.f;
    float ws[8] = {0.f, 0.f, 0.f, 0.f, 0.f, 0.f, 0.f, 0.f};
    for (int k = c; k < deg; k += 16) {
        float e;
        if (k < CCAP) {
            e = __expf(ecache[w][k * 4 + h] - mxh);
            ecache[w][k * 4 + h] = e;
            half8 ev = eac[w][k];
#pragma unroll
            for (int i = 0; i < 8; ++i) ws[i] = fmaf(e, (float)ev[i], ws[i]);
        } else {                               // cold: deg > CCAP
            int2 pr = csr2[beg + k];
            float4 ssv = *(const float4*)&ss[(nbase + pr.y) * HQ];
            float ssh = (h == 0) ? ssv.x : (h == 1) ? ssv.y : (h == 2) ? ssv.z : ssv.w;
            const float4* eap = (const float4*)(ef + (ebase + pr.x) * EDQ);
            float4 lo = eap[0], hi = eap[1];
            float se =      lo.x * WA[0 * 4 + h];
            se = fmaf(lo.y, WA[1 * 4 + h], se); se = fmaf(lo.z, WA[2 * 4 + h], se);
            se = fmaf(lo.w, WA[3 * 4 + h], se); se = fmaf(hi.x, WA[4 * 4 + h], se);
            se = fmaf(hi.y, WA[5 * 4 + h], se); se = fmaf(hi.z, WA[6 * 4 + h], se);
            se = fmaf(hi.w, WA[7 * 4 + h], se);
            float sc = sdh + ssh + se;
            sc = (sc >= 0.f) ? sc : 0.2f * sc;
            e = __expf(sc - mxh);
            ws[0] = fmaf(e, lo.x, ws[0]); ws[1] = fmaf(e, lo.y, ws[1]);
            ws[2] = fmaf(e, lo.z, ws[2]); ws[3] = fmaf(e, lo.w, ws[3]);
            ws[4] = fmaf(e, hi.x, ws[4]); ws[5] = fmaf(e, hi.y, ws[5]);
            ws[6] = fmaf(e, hi.z, ws[6]); ws[7] = fmaf(e, hi.w, ws[7]);
        }
        sum += e;
    }
#pragma unroll
    for (int s = 1; s < 16; s <<= 1) {
        sum += __shfl_xor(sum, s, 16);
#pragma unroll
        for (int i = 0; i < 8; ++i) ws[i] += __shfl_xor(ws[i], s, 16);
    }
    float inv = 1.f / (sum + 1e-16f);
#pragma unroll
    for (int i = 0; i < 8; ++i) ws[i] *= inv;
    // ---- pass 3 (edge-parallel): half4 alpha store --------------------------
    float inv4[4];
#pragma unroll
    for (int hh = 0; hh < 4; ++hh) inv4[hh] = __shfl(inv, hh * 16, 64);
    for (int k = lane; k < deg; k += 64) {
        float e4[4]; int eid;
        if (k < CCAP) {
            eid = eids[w][k];
            float4 ev = *(const float4*)&ecache[w][k * 4];
            e4[0] = ev.x; e4[1] = ev.y; e4[2] = ev.z; e4[3] = ev.w;
        } else {
            int2 pr = csr2[beg + k];
            eid = pr.x;
            float4 ssv = *(const float4*)&ss[(nbase + pr.y) * HQ];
            const float4* eap = (const float4*)(ef + (ebase + pr.x) * EDQ);
            float4 lo = eap[0], hi = eap[1];
#pragma unroll
            for (int hh = 0; hh < 4; ++hh) {
                float se =      lo.x * WA[0 * 4 + hh];
                se = fmaf(lo.y, WA[1 * 4 + hh], se); se = fmaf(lo.z, WA[2 * 4 + hh], se);
                se = fmaf(lo.w, WA[3 * 4 + hh], se); se = fmaf(hi.x, WA[4 * 4 + hh], se);
                se = fmaf(hi.y, WA[5 * 4 + hh], se); se = fmaf(hi.z, WA[6 * 4 + hh], se);
                se = fmaf(hi.w, WA[7 * 4 + hh], se);
                float sdh2 = (hh == 0) ? sd4.x : (hh == 1) ? sd4.y : (hh == 2) ? sd4.z : sd4.w;
                float ssh2 = (hh == 0) ? ssv.x : (hh == 1) ? ssv.y : (hh == 2) ? ssv.z : ssv.w;
                float sc = sdh2 + ssh2 + se;
                sc = (sc >= 0.f) ? sc : 0.2f * sc;
                e4[hh] = __expf(sc - mxr[hh]);
            }
        }
        half4v av;
        av[0] = (_Float16)(e4[0] * inv4[0]); av[1] = (_Float16)(e4[1] * inv4[1]);
        av[2] = (_Float16)(e4[2] * inv4[2]); av[3] = (_Float16)(e4[3] * inv4[3]);
        *(half4v*)&alphaH[(ebase + eid) * HQ] = av;
    }
    // ---- phase B: aggregate alpha*h[src], ELU + LN --------------------------
    float acc = 0.f;
#pragma unroll
    for (int k = 0; k < PF; ++k)
        if (k < dpf) acc = fmaf(ecache[w][k * 4 + h], (float)hpre[k], acc);
#pragma unroll 4
    for (int k = dpf; k < dmain; ++k) {
        float e0 = ecache[w][k * 4 + h];
        float h0 = (float)hp[(size_t)srcs[w][k] * GQ];
        acc = fmaf(e0, h0, acc);
    }
    for (int k = dmain; k < deg; ++k) {        // cold path
        int2 pr = csr2[beg + k];
        float4 ssv = *(const float4*)&ss[(nbase + pr.y) * HQ];
        float ssh = (h == 0) ? ssv.x : (h == 1) ? ssv.y : (h == 2) ? ssv.z : ssv.w;
        const float4* eap = (const float4*)(ef + (ebase + pr.x) * EDQ);
        float4 lo = eap[0], hi = eap[1];
        float se =      lo.x * WA[0 * 4 + h];
        se = fmaf(lo.y, WA[1 * 4 + h], se); se = fmaf(lo.z, WA[2 * 4 + h], se);
        se = fmaf(lo.w, WA[3 * 4 + h], se); se = fmaf(hi.x, WA[4 * 4 + h], se);
        se = fmaf(hi.y, WA[5 * 4 + h], se); se = fmaf(hi.z, WA[6 * 4 + h], se);
        se = fmaf(hi.w, WA[7 * 4 + h], se);
        float sc = sdh + ssh + se;
        sc = (sc >= 0.f) ? sc : 0.2f * sc;
        float e0 = __expf(sc - mxh);
        float h0 = (float)hp[(size_t)pr.y * GQ];
        acc = fmaf(e0, h0, acc);
    }
    acc *= inv;
    float t2 = 0.f;
#pragma unroll
    for (int i = 0; i < 8; ++i) t2 = fmaf(ws[i], Wl[i * GQ + lane], t2);
    float x = acc + t2;
    x = (x > 0.f) ? x : (__expf(x) - 1.f);     // ELU
    float s1 = x, s2v = x * x;
#pragma unroll
    for (int s = 32; s >= 1; s >>= 1) {
        s1 += __shfl_xor(s1, s, 64);
        s2v += __shfl_xor(s2v, s, 64);
    }
    float mu = s1 * (1.f / 64.f);
    float var = s2v * (1.f / 64.f) - mu * mu;
    float y = (x - mu) * rsqrtf(var + LN_EPSQ) * gamma[lane] + beta[lane];
    spatialH[(nbase + n) * GQ + lane] = (_Float16)y;
}

// -------------------- GRU via MFMA (f16 inputs, f32 accum) -------------------
// block = 16 sequences, 4 waves; wave w owns hidden cols [16w,16w+16)
__device__ inline f32x4 MF(half8 a, half8 b, f32x4 c) {
    return __builtin_amdgcn_mfma_f32_16x16x32_f16(a, b, c, 0, 0, 0);
}

__global__ void __launch_bounds__(256) k_gru(
        const _Float16* __restrict__ xh,     // [48][2000][64] f16 (g = b*12+t)
        const float* __restrict__ Wih, const float* __restrict__ Whh,
        const float* __restrict__ bih, const float* __restrict__ bhh,
        const float* __restrict__ Wout, const float* __restrict__ bout,
        float* __restrict__ out) {
    __shared__ _Float16 hlds[16][72];          // +8 pad: 144B row stride
    __shared__ float pred_s[4][16];
    int tid = threadIdx.x;
    int w = tid >> 6, l = tid & 63;
    int lr = l & 15, lg = l >> 4;
    int j = w * 16 + lr;                       // this lane's hidden/gate column
    half8 wiF[3][2], whF[3][2];
#pragma unroll
    for (int gb = 0; gb < 3; ++gb) {
        int q = gb * 64 + j;
#pragma unroll
        for (int kt = 0; kt < 2; ++kt) {
            const float* p  = Wih + q * 64 + kt * 32 + lg * 8;
            const float* p2 = Whh + q * 64 + kt * 32 + lg * 8;
            half8 a, b;
#pragma unroll
            for (int i = 0; i < 8; ++i) { a[i] = (_Float16)p[i]; b[i] = (_Float16)p2[i]; }
            wiF[gb][kt] = a; whF[gb][kt] = b;
        }
    }
    float br  = bih[j] + bhh[j];
    float bz  = bih[64 + j] + bhh[64 + j];
    float bin = bih[128 + j];
    float bhn = bhh[128 + j];
    float wo  = Wout[j];
    for (int i = tid; i < 16 * 72; i += 256) ((_Float16*)hlds)[i] = (_Float16)0.f;
    int id0 = blockIdx.x * 16;
    const _Float16* xp0;
    {
        int id = id0 + lr;
        int b = id / NQ, n = id - b * NQ;
        xp0 = xh + ((size_t)b * TQ * NQ + n) * GQ + lg * 8;
    }
    half8 xa[2];
    xa[0] = *(const half8*)xp0; xa[1] = *(const half8*)(xp0 + 32);
    float hprev[4] = {0.f, 0.f, 0.f, 0.f};
    __syncthreads();
    for (int t = 0; t < TQ; ++t) {
        f32x4 aR  = (f32x4){br, br, br, br};
        f32x4 aZ  = (f32x4){bz, bz, bz, bz};
        f32x4 aIN = (f32x4){bin, bin, bin, bin};
        f32x4 aHN = (f32x4){bhn, bhn, bhn, bhn};
#pragma unroll
        for (int kt = 0; kt < 2; ++kt) {
            aR  = MF(xa[kt], wiF[0][kt], aR);
            aZ  = MF(xa[kt], wiF[1][kt], aZ);
            aIN = MF(xa[kt], wiF[2][kt], aIN);
        }
        half8 ha[2];
        ha[0] = *(const half8*)&hlds[lr][lg * 8];
        ha[1] = *(const half8*)&hlds[lr][32 + lg * 8];
#pragma unroll
        for (int kt = 0; kt < 2; ++kt) {
            aR  = MF(ha[kt], whF[0][kt], aR);
            aZ  = MF(ha[kt], whF[1][kt], aZ);
            aHN = MF(ha[kt], whF[2][kt], aHN);
        }
        if (t + 1 < TQ) {
            xp0 += (size_t)NQ * GQ;
            xa[0] = *(const half8*)xp0; xa[1] = *(const half8*)(xp0 + 32);
        }
#pragma unroll
        for (int r4 = 0; r4 < 4; ++r4) {
            float r = 1.f / (1.f + __expf(-aR[r4]));
            float z = 1.f / (1.f + __expf(-aZ[r4]));
            float xg = aIN[r4] + r * aHN[r4];
            float e2 = __expf(2.f * xg);
            float nn = 1.f - 2.f / (e2 + 1.f);     // tanh(xg)
            hprev[r4] = z * (hprev[r4] - nn) + nn;
        }
        __syncthreads();
#pragma unroll
        for (int r4 = 0; r4 < 4; ++r4)
            hlds[4 * lg + r4][j] = (_Float16)hprev[r4];
        __syncthreads();
    }
    float pv[4];
#pragma unroll
    for (int r4 = 0; r4 < 4; ++r4) {
        int id = id0 + 4 * lg + r4;
        out[8000 + (size_t)id * GHQ + j] = hprev[r4];
        pv[r4] = hprev[r4] * wo;
    }
#pragma unroll
    for (int s = 1; s <= 8; s <<= 1)
#pragma unroll
        for (int r4 = 0; r4 < 4; ++r4)
            pv[r4] += __shfl_xor(pv[r4], s);
    if (lr == 0) {
#pragma unroll
        for (int r4 = 0; r4 < 4; ++r4)
            pred_s[w][4 * lg + r4] = pv[r4];
    }
    __syncthreads();
    if (tid < 16) {
        float s = pred_s[0][tid] + pred_s[1][tid] + pred_s[2][tid] + pred_s[3][tid] + bout[0];
        out[id0 + tid] = s;
    }
}

// -------------------- attention mean over batch (f16 in) ---------------------
__global__ void k_attn(const _Float16* __restrict__ alpha, float* __restrict__ out) {
    int gid = blockIdx.x * blockDim.x + threadIdx.x;   // t*EQ + e
    if (gid >= TQ * EQ) return;
    int tt = gid / EQ, e = gid % EQ;
    float a0 = 0.f, a1 = 0.f, a2 = 0.f, a3 = 0.f;
#pragma unroll
    for (int b = 0; b < BQ; ++b) {
        half4v v = *(const half4v*)&alpha[(((size_t)b * TQ + tt) * EQ + e) * HQ];
        a0 += (float)v[0]; a1 += (float)v[1]; a2 += (float)v[2]; a3 += (float)v[3];
    }
    float4 r = {a0 * 0.25f, a1 * 0.25f, a2 * 0.25f, a3 * 0.25f};
    *(float4*)&out[ATTN_OFF + (size_t)gid * HQ] = r;
}

extern "C" void kernel_launch(void* const* d_in, const int* in_sizes, int n_in,
                              void* d_out, int out_size, void* d_ws, size_t ws_size,
                              hipStream_t stream) {
    const float* nodef = (const float*)d_in[0];
    const float* edgef = (const float*)d_in[1];
    const float* Wn    = (const float*)d_in[2];
    const float* We    = (const float*)d_in[3];
    const float* att   = (const float*)d_in[4];
    const float* gamma = (const float*)d_in[5];
    const float* beta  = (const float*)d_in[6];
    const float* Wih   = (const float*)d_in[7];
    const float* Whh   = (const float*)d_in[8];
    const float* bih   = (const float*)d_in[9];
    const float* bhh   = (const float*)d_in[10];
    const float* Wout  = (const float*)d_in[11];
    const float* bout  = (const float*)d_in[12];
    const int*   ei    = (const int*)d_in[13];

    char* ws = (char*)d_ws;
    size_t o = 0;
    int*  count  = (int*)(ws + o);  o += 2048 * 4;
    int*  offs   = (int*)(ws + o);  o += 2048 * 4;
    int*  cursor = (int*)(ws + o);  o += 2048 * 4;
    int2* csr2   = (int2*)(ws + o); o += (size_t)EQ * 8;
    float* sd      = (float*)(ws + o); o += (size_t)NGQ * NQ * HQ * 4;
    float* ss      = (float*)(ws + o); o += (size_t)NGQ * NQ * HQ * 4;
    _Float16* hprojH   = (_Float16*)(ws + o); o += (size_t)NGQ * NQ * GQ * 2;
    _Float16* alphaH   = (_Float16*)(ws + o); o += (size_t)NGQ * EQ * HQ * 2;
    _Float16* spatialH = (_Float16*)(ws + o); o += (size_t)NGQ * NQ * GQ * 2;

    hipMemsetAsync(count, 0, NQ * sizeof(int), stream);
    k_count  <<<(EQ + 255) / 256, 256, 0, stream>>>(ei, count);
    k_scan   <<<1, 1024, 0, stream>>>(count, offs, cursor);
    k_scatter<<<(EQ + 255) / 256, 256, 0, stream>>>(ei, cursor, csr2);

    k_nodeproj<<<(NGQ * NQ) / 256, 256, 0, stream>>>(nodef, Wn, att, hprojH, sd, ss);
    k_fused   <<<(NGQ * NQ) / 4, 256, 0, stream>>>(edgef, We, att, offs, csr2,
                                                   sd, ss, hprojH, gamma, beta,
                                                   alphaH, spatialH);
    k_gru     <<<(BQ * NQ) / 16, 256, 0, stream>>>(spatialH, Wih, Whh, bih, bhh,
                                                   Wout, bout, (float*)d_out);
    k_attn    <<<(TQ * EQ + 255) / 256, 256, 0, stream>>>(alphaH, (float*)d_out);
}

// Round 8
// 284.092 us; speedup vs baseline: 1.6685x; 1.3785x over previous
//
#include <hip/hip_runtime.h>
#include <hip/hip_bf16.h>
#include <math.h>
#include <stdint.h>

#define BQ 4
#define TQ 12
#define NQ 2000
#define EQ 32000
#define NDQ 16
#define EDQ 8
#define HQ 4
#define DQ 16
#define GQ 64
#define GHQ 64
#define NGQ 48          // B*T graphs
#define LN_EPSQ 1e-5f
#define CCAP 64         // LDS edge cache per node (deg>CCAP falls back to global)
#define ATTN_OFF 520000 // pred(8000) + h_i(512000)

typedef _Float16 half8 __attribute__((ext_vector_type(8)));
typedef _Float16 half4v __attribute__((ext_vector_type(4)));
typedef float f32x4 __attribute__((ext_vector_type(4)));

// -------------------- CSR build (edge_index shared across graphs) ------------
__global__ void k_count(const int* __restrict__ ei, int* __restrict__ count) {
    int e = blockIdx.x * blockDim.x + threadIdx.x;
    if (e < EQ) atomicAdd(&count[ei[EQ + e]], 1);
}

__global__ void k_scan(const int* __restrict__ count, int* __restrict__ offs,
                       int* __restrict__ cursor) {
    __shared__ int buf[2][2048];
    int t = threadIdx.x;                       // 1024 threads
    for (int i = t; i < 2048; i += 1024)
        buf[0][i] = (i < NQ) ? count[i] : 0;
    __syncthreads();
    int src = 0;
    for (int sh = 1; sh < 2048; sh <<= 1) {
        int dst = src ^ 1;
        for (int i = t; i < 2048; i += 1024) {
            int v = buf[src][i];
            if (i >= sh) v += buf[src][i - sh];
            buf[dst][i] = v;
        }
        __syncthreads();
        src = dst;
    }
    for (int i = t; i <= NQ; i += 1024) {
        int off = (i == 0) ? 0 : buf[src][i - 1];
        offs[i] = off;
        if (i < NQ) cursor[i] = off;
    }
}

__global__ void k_scatter(const int* __restrict__ ei, int* __restrict__ cursor,
                          int2* __restrict__ csr2) {
    int e = blockIdx.x * blockDim.x + threadIdx.x;
    if (e < EQ) {
        int pos = atomicAdd(&cursor[ei[EQ + e]], 1);
        csr2[pos] = make_int2(e, ei[e]);       // (eid, src)
    }
}

// -------------------- node projection: one THREAD per (g,n) ------------------
__global__ void __launch_bounds__(256) k_nodeproj(
        const float* __restrict__ xf, const float* __restrict__ Wn,
        const float* __restrict__ att,
        _Float16* __restrict__ hprojH, float* __restrict__ sd,
        float* __restrict__ ss) {
    __shared__ __align__(16) float4 Wl4[NDQ * 16];   // [i][j4] row-major, 4KB
    __shared__ float attl[HQ * 48];
    int t = threadIdx.x;
    for (int i = t; i < NDQ * 16; i += 256) Wl4[i] = ((const float4*)Wn)[i];
    if (t < HQ * 48) attl[t] = att[t];
    __syncthreads();
    int id = blockIdx.x * 256 + t;                   // g*NQ + n, total 96000
    const float4* xp = (const float4*)(xf + (size_t)id * NDQ);
    float4 xv0 = xp[0], xv1 = xp[1], xv2 = xp[2], xv3 = xp[3];
    float xr[16] = {xv0.x, xv0.y, xv0.z, xv0.w, xv1.x, xv1.y, xv1.z, xv1.w,
                    xv2.x, xv2.y, xv2.z, xv2.w, xv3.x, xv3.y, xv3.z, xv3.w};
    float acc[64];
#pragma unroll
    for (int j = 0; j < 64; ++j) acc[j] = 0.f;
#pragma unroll
    for (int i = 0; i < 16; ++i) {
        float xi = xr[i];
#pragma unroll
        for (int j4 = 0; j4 < 16; ++j4) {
            float4 wv = Wl4[i * 16 + j4];            // uniform addr: broadcast
            acc[j4 * 4 + 0] = fmaf(xi, wv.x, acc[j4 * 4 + 0]);
            acc[j4 * 4 + 1] = fmaf(xi, wv.y, acc[j4 * 4 + 1]);
            acc[j4 * 4 + 2] = fmaf(xi, wv.z, acc[j4 * 4 + 2]);
            acc[j4 * 4 + 3] = fmaf(xi, wv.w, acc[j4 * 4 + 3]);
        }
    }
    float sdv[4], ssv[4];
#pragma unroll
    for (int hh = 0; hh < 4; ++hh) {
        float vd = 0.f, vs = 0.f;
#pragma unroll
        for (int d = 0; d < 16; ++d) {
            vd = fmaf(acc[hh * 16 + d], attl[hh * 48 + d], vd);
            vs = fmaf(acc[hh * 16 + d], attl[hh * 48 + 16 + d], vs);
        }
        sdv[hh] = vd; ssv[hh] = vs;
    }
    *(float4*)&sd[(size_t)id * 4] = make_float4(sdv[0], sdv[1], sdv[2], sdv[3]);
    *(float4*)&ss[(size_t)id * 4] = make_float4(ssv[0], ssv[1], ssv[2], ssv[3]);
#pragma unroll
    for (int p = 0; p < 8; ++p) {
        half8 hv;
#pragma unroll
        for (int i = 0; i < 8; ++i) hv[i] = (_Float16)acc[p * 8 + i];
        *(half8*)&hprojH[(size_t)id * GQ + p * 8] = hv;
    }
}

// ------ fused: edge-score + softmax + aggregate + ELU + LN (wave per node) ---
// pass 1: lane = edge (global loads once, cache to LDS, head-max reduce)
// pass 2/3: lane = (h, c) over LDS; phase B: lane = output feature j
// (RESTORED to the R4-measured configuration: 135 us, VALUBusy 60%, occ 60%)
__global__ void __launch_bounds__(256) k_fused(
        const float* __restrict__ ef, const float* __restrict__ We,
        const float* __restrict__ att,
        const int* __restrict__ offs, const int2* __restrict__ csr2,
        const float* __restrict__ sd, const float* __restrict__ ss,
        const _Float16* __restrict__ hprojH,
        const float* __restrict__ gamma, const float* __restrict__ beta,
        _Float16* __restrict__ alphaH, _Float16* __restrict__ spatialH) {
    __shared__ float Wl[EDQ * GQ];                       // 2KB: We staged
    __shared__ __align__(16) float WA[EDQ * HQ];         // [i][h] factored edge-attn
    __shared__ __align__(16) float ecache[4][CCAP * 4];  // 4KB: score->exp per (edge,h)
    __shared__ half8 eac[4][CCAP];                       // 4KB: ea as f16x8
    __shared__ int   srcs[4][CCAP];                      // 1KB
    __shared__ int   eids[4][CCAP];                      // 1KB
    int t = threadIdx.x;
    for (int i = t; i < EDQ * GQ; i += 256) Wl[i] = We[i];
    if (t < EDQ * HQ) {
        int i = t >> 2, h4 = t & 3;
        float s = 0.f;
#pragma unroll
        for (int d = 0; d < DQ; ++d)
            s = fmaf(We[i * GQ + h4 * DQ + d], att[h4 * 48 + 32 + d], s);
        WA[t] = s;
    }
    __syncthreads();
    int w = t >> 6, lane = t & 63;
    int wid = blockIdx.x * 4 + w;              // exact: grid = NGQ*NQ/4
    int g = wid / NQ, n = wid % NQ;
    int beg = offs[n], deg = offs[n + 1] - beg;
    size_t ebase = (size_t)g * EQ;
    size_t nbase = (size_t)g * NQ;
    float4 sd4 = *(const float4*)&sd[(nbase + n) * HQ];
    // ---- pass 1 (edge-parallel): load once, score all heads, cache ---------
    float mxr[4] = {-1e30f, -1e30f, -1e30f, -1e30f};
    for (int k = lane; k < deg; k += 64) {
        int2 pr = csr2[beg + k];
        float4 ssv = *(const float4*)&ss[(nbase + pr.y) * HQ];
        const float4* eap = (const float4*)(ef + (ebase + pr.x) * EDQ);
        float4 lo = eap[0], hi = eap[1];
        float scv[4];
#pragma unroll
        for (int hh = 0; hh < 4; ++hh) {
            float se =      lo.x * WA[0 * 4 + hh];
            se = fmaf(lo.y, WA[1 * 4 + hh], se); se = fmaf(lo.z, WA[2 * 4 + hh], se);
            se = fmaf(lo.w, WA[3 * 4 + hh], se); se = fmaf(hi.x, WA[4 * 4 + hh], se);
            se = fmaf(hi.y, WA[5 * 4 + hh], se); se = fmaf(hi.z, WA[6 * 4 + hh], se);
            se = fmaf(hi.w, WA[7 * 4 + hh], se);
            float sdh = (hh == 0) ? sd4.x : (hh == 1) ? sd4.y : (hh == 2) ? sd4.z : sd4.w;
            float ssh = (hh == 0) ? ssv.x : (hh == 1) ? ssv.y : (hh == 2) ? ssv.z : ssv.w;
            float sc = sdh + ssh + se;
            sc = (sc >= 0.f) ? sc : 0.2f * sc;
            scv[hh] = sc;
            mxr[hh] = fmaxf(mxr[hh], sc);
        }
        if (k < CCAP) {
            *(float4*)&ecache[w][k * 4] = make_float4(scv[0], scv[1], scv[2], scv[3]);
            half8 hv;
            hv[0] = (_Float16)lo.x; hv[1] = (_Float16)lo.y;
            hv[2] = (_Float16)lo.z; hv[3] = (_Float16)lo.w;
            hv[4] = (_Float16)hi.x; hv[5] = (_Float16)hi.y;
            hv[6] = (_Float16)hi.z; hv[7] = (_Float16)hi.w;
            eac[w][k] = hv;
            srcs[w][k] = pr.y;
            eids[w][k] = pr.x;
        }
    }
#pragma unroll
    for (int s = 1; s < 64; s <<= 1) {
#pragma unroll
        for (int hh = 0; hh < 4; ++hh)
            mxr[hh] = fmaxf(mxr[hh], __shfl_xor(mxr[hh], s, 64));
    }
    int h = lane >> 4, c = lane & 15;
    float mxh = (h == 0) ? mxr[0] : (h == 1) ? mxr[1] : (h == 2) ? mxr[2] : mxr[3];
    float sdh = (h == 0) ? sd4.x : (h == 1) ? sd4.y : (h == 2) ? sd4.z : sd4.w;
    // ---- pass 2 (LDS): exp, sum, weighted edge-feature sums ----------------
    float sum = 0.f;
    float ws[8] = {0.f, 0.f, 0.f, 0.f, 0.f, 0.f, 0.f, 0.f};
    for (int k = c; k < deg; k += 16) {
        float e;
        if (k < CCAP) {
            e = __expf(ecache[w][k * 4 + h] - mxh);
            ecache[w][k * 4 + h] = e;
            half8 ev = eac[w][k];
#pragma unroll
            for (int i = 0; i < 8; ++i) ws[i] = fmaf(e, (float)ev[i], ws[i]);
        } else {                               // cold: deg > CCAP
            int2 pr = csr2[beg + k];
            float4 ssv = *(const float4*)&ss[(nbase + pr.y) * HQ];
            float ssh = (h == 0) ? ssv.x : (h == 1) ? ssv.y : (h == 2) ? ssv.z : ssv.w;
            const float4* eap = (const float4*)(ef + (ebase + pr.x) * EDQ);
            float4 lo = eap[0], hi = eap[1];
            float se =      lo.x * WA[0 * 4 + h];
            se = fmaf(lo.y, WA[1 * 4 + h], se); se = fmaf(lo.z, WA[2 * 4 + h], se);
            se = fmaf(lo.w, WA[3 * 4 + h], se); se = fmaf(hi.x, WA[4 * 4 + h], se);
            se = fmaf(hi.y, WA[5 * 4 + h], se); se = fmaf(hi.z, WA[6 * 4 + h], se);
            se = fmaf(hi.w, WA[7 * 4 + h], se);
            float sc = sdh + ssh + se;
            sc = (sc >= 0.f) ? sc : 0.2f * sc;
            e = __expf(sc - mxh);
            ws[0] = fmaf(e, lo.x, ws[0]); ws[1] = fmaf(e, lo.y, ws[1]);
            ws[2] = fmaf(e, lo.z, ws[2]); ws[3] = fmaf(e, lo.w, ws[3]);
            ws[4] = fmaf(e, hi.x, ws[4]); ws[5] = fmaf(e, hi.y, ws[5]);
            ws[6] = fmaf(e, hi.z, ws[6]); ws[7] = fmaf(e, hi.w, ws[7]);
        }
        sum += e;
    }
#pragma unroll
    for (int s = 1; s < 16; s <<= 1) {
        sum += __shfl_xor(sum, s, 16);
#pragma unroll
        for (int i = 0; i < 8; ++i) ws[i] += __shfl_xor(ws[i], s, 16);
    }
    float inv = 1.f / (sum + 1e-16f);
#pragma unroll
    for (int i = 0; i < 8; ++i) ws[i] *= inv;
    // ---- pass 3: write normalized alpha (f16) ------------------------------
    for (int k = c; k < deg; k += 16) {
        float e; int eid;
        if (k < CCAP) {
            e = ecache[w][k * 4 + h];
            eid = eids[w][k];
        } else {
            int2 pr = csr2[beg + k];
            eid = pr.x;
            float4 ssv = *(const float4*)&ss[(nbase + pr.y) * HQ];
            float ssh = (h == 0) ? ssv.x : (h == 1) ? ssv.y : (h == 2) ? ssv.z : ssv.w;
            const float4* eap = (const float4*)(ef + (ebase + pr.x) * EDQ);
            float4 lo = eap[0], hi = eap[1];
            float se =      lo.x * WA[0 * 4 + h];
            se = fmaf(lo.y, WA[1 * 4 + h], se); se = fmaf(lo.z, WA[2 * 4 + h], se);
            se = fmaf(lo.w, WA[3 * 4 + h], se); se = fmaf(hi.x, WA[4 * 4 + h], se);
            se = fmaf(hi.y, WA[5 * 4 + h], se); se = fmaf(hi.z, WA[6 * 4 + h], se);
            se = fmaf(hi.w, WA[7 * 4 + h], se);
            float sc = sdh + ssh + se;
            sc = (sc >= 0.f) ? sc : 0.2f * sc;
            e = __expf(sc - mxh);
        }
        alphaH[(ebase + eid) * HQ + h] = (_Float16)(e * inv);
    }
    // ---- phase B: aggregate alpha*h[src] (f16 gathers), ELU + LN -----------
    int dmain = deg < CCAP ? deg : CCAP;
    const _Float16* hp = hprojH + nbase * GQ + lane;
    float acc = 0.f;
    int k = 0;
    for (; k + 8 <= dmain; k += 8) {
        float e0 = ecache[w][(k + 0) * 4 + h], e1 = ecache[w][(k + 1) * 4 + h];
        float e2 = ecache[w][(k + 2) * 4 + h], e3 = ecache[w][(k + 3) * 4 + h];
        float e4 = ecache[w][(k + 4) * 4 + h], e5 = ecache[w][(k + 5) * 4 + h];
        float e6 = ecache[w][(k + 6) * 4 + h], e7 = ecache[w][(k + 7) * 4 + h];
        float h0 = (float)hp[(size_t)srcs[w][k + 0] * GQ];
        float h1 = (float)hp[(size_t)srcs[w][k + 1] * GQ];
        float h2 = (float)hp[(size_t)srcs[w][k + 2] * GQ];
        float h3 = (float)hp[(size_t)srcs[w][k + 3] * GQ];
        float h4 = (float)hp[(size_t)srcs[w][k + 4] * GQ];
        float h5 = (float)hp[(size_t)srcs[w][k + 5] * GQ];
        float h6 = (float)hp[(size_t)srcs[w][k + 6] * GQ];
        float h7 = (float)hp[(size_t)srcs[w][k + 7] * GQ];
        acc = fmaf(e0, h0, acc); acc = fmaf(e1, h1, acc);
        acc = fmaf(e2, h2, acc); acc = fmaf(e3, h3, acc);
        acc = fmaf(e4, h4, acc); acc = fmaf(e5, h5, acc);
        acc = fmaf(e6, h6, acc); acc = fmaf(e7, h7, acc);
    }
    for (; k < dmain; ++k) {
        float e0 = ecache[w][k * 4 + h];
        float h0 = (float)hp[(size_t)srcs[w][k] * GQ];
        acc = fmaf(e0, h0, acc);
    }
    for (; k < deg; ++k) {                     // cold path
        int2 pr = csr2[beg + k];
        float4 ssv = *(const float4*)&ss[(nbase + pr.y) * HQ];
        float ssh = (h == 0) ? ssv.x : (h == 1) ? ssv.y : (h == 2) ? ssv.z : ssv.w;
        const float4* eap = (const float4*)(ef + (ebase + pr.x) * EDQ);
        float4 lo = eap[0], hi = eap[1];
        float se =      lo.x * WA[0 * 4 + h];
        se = fmaf(lo.y, WA[1 * 4 + h], se); se = fmaf(lo.z, WA[2 * 4 + h], se);
        se = fmaf(lo.w, WA[3 * 4 + h], se); se = fmaf(hi.x, WA[4 * 4 + h], se);
        se = fmaf(hi.y, WA[5 * 4 + h], se); se = fmaf(hi.z, WA[6 * 4 + h], se);
        se = fmaf(hi.w, WA[7 * 4 + h], se);
        float sc = sdh + ssh + se;
        sc = (sc >= 0.f) ? sc : 0.2f * sc;
        float e0 = __expf(sc - mxh);
        float h0 = (float)hp[(size_t)pr.y * GQ];
        acc = fmaf(e0, h0, acc);
    }
    acc *= inv;
    float t2 = 0.f;
#pragma unroll
    for (int i = 0; i < 8; ++i) t2 = fmaf(ws[i], Wl[i * GQ + lane], t2);
    float x = acc + t2;
    x = (x > 0.f) ? x : (__expf(x) - 1.f);     // ELU
    float s1 = x, s2v = x * x;
#pragma unroll
    for (int s = 32; s >= 1; s >>= 1) {
        s1 += __shfl_xor(s1, s, 64);
        s2v += __shfl_xor(s2v, s, 64);
    }
    float mu = s1 * (1.f / 64.f);
    float var = s2v * (1.f / 64.f) - mu * mu;
    float y = (x - mu) * rsqrtf(var + LN_EPSQ) * gamma[lane] + beta[lane];
    spatialH[(nbase + n) * GQ + lane] = (_Float16)y;
}

// -------------------- GRU via MFMA (f16 inputs, f32 accum) -------------------
// block = 16 sequences, 4 waves; wave w owns hidden cols [16w,16w+16)
__device__ inline f32x4 MF(half8 a, half8 b, f32x4 c) {
    return __builtin_amdgcn_mfma_f32_16x16x32_f16(a, b, c, 0, 0, 0);
}

__global__ void __launch_bounds__(256) k_gru(
        const _Float16* __restrict__ xh,     // [48][2000][64] f16 (g = b*12+t)
        const float* __restrict__ Wih, const float* __restrict__ Whh,
        const float* __restrict__ bih, const float* __restrict__ bhh,
        const float* __restrict__ Wout, const float* __restrict__ bout,
        float* __restrict__ out) {
    __shared__ _Float16 hlds[16][72];          // +8 pad: 144B row stride
    __shared__ float pred_s[4][16];
    int tid = threadIdx.x;
    int w = tid >> 6, l = tid & 63;
    int lr = l & 15, lg = l >> 4;
    int j = w * 16 + lr;                       // this lane's hidden/gate column
    half8 wiF[3][2], whF[3][2];
#pragma unroll
    for (int gb = 0; gb < 3; ++gb) {
        int q = gb * 64 + j;
#pragma unroll
        for (int kt = 0; kt < 2; ++kt) {
            const float* p  = Wih + q * 64 + kt * 32 + lg * 8;
            const float* p2 = Whh + q * 64 + kt * 32 + lg * 8;
            half8 a, b;
#pragma unroll
            for (int i = 0; i < 8; ++i) { a[i] = (_Float16)p[i]; b[i] = (_Float16)p2[i]; }
            wiF[gb][kt] = a; whF[gb][kt] = b;
        }
    }
    float br  = bih[j] + bhh[j];
    float bz  = bih[64 + j] + bhh[64 + j];
    float bin = bih[128 + j];
    float bhn = bhh[128 + j];
    float wo  = Wout[j];
    for (int i = tid; i < 16 * 72; i += 256) ((_Float16*)hlds)[i] = (_Float16)0.f;
    int id0 = blockIdx.x * 16;
    const _Float16* xp0;
    {
        int id = id0 + lr;
        int b = id / NQ, n = id - b * NQ;
        xp0 = xh + ((size_t)b * TQ * NQ + n) * GQ + lg * 8;
    }
    half8 xa[2];
    xa[0] = *(const half8*)xp0; xa[1] = *(const half8*)(xp0 + 32);
    float hprev[4] = {0.f, 0.f, 0.f, 0.f};
    __syncthreads();
    for (int t = 0; t < TQ; ++t) {
        f32x4 aR  = (f32x4){br, br, br, br};
        f32x4 aZ  = (f32x4){bz, bz, bz, bz};
        f32x4 aIN = (f32x4){bin, bin, bin, bin};
        f32x4 aHN = (f32x4){bhn, bhn, bhn, bhn};
#pragma unroll
        for (int kt = 0; kt < 2; ++kt) {
            aR  = MF(xa[kt], wiF[0][kt], aR);
            aZ  = MF(xa[kt], wiF[1][kt], aZ);
            aIN = MF(xa[kt], wiF[2][kt], aIN);
        }
        half8 ha[2];
        ha[0] = *(const half8*)&hlds[lr][lg * 8];
        ha[1] = *(const half8*)&hlds[lr][32 + lg * 8];
#pragma unroll
        for (int kt = 0; kt < 2; ++kt) {
            aR  = MF(ha[kt], whF[0][kt], aR);
            aZ  = MF(ha[kt], whF[1][kt], aZ);
            aHN = MF(ha[kt], whF[2][kt], aHN);
        }
        if (t + 1 < TQ) {
            xp0 += (size_t)NQ * GQ;
            xa[0] = *(const half8*)xp0; xa[1] = *(const half8*)(xp0 + 32);
        }
#pragma unroll
        for (int r4 = 0; r4 < 4; ++r4) {
            float r = 1.f / (1.f + __expf(-aR[r4]));
            float z = 1.f / (1.f + __expf(-aZ[r4]));
            float xg = aIN[r4] + r * aHN[r4];
            float e2 = __expf(2.f * xg);
            float nn = 1.f - 2.f / (e2 + 1.f);     // tanh(xg)
            hprev[r4] = z * (hprev[r4] - nn) + nn;
        }
        __syncthreads();
#pragma unroll
        for (int r4 = 0; r4 < 4; ++r4)
            hlds[4 * lg + r4][j] = (_Float16)hprev[r4];
        __syncthreads();
    }
    float pv[4];
#pragma unroll
    for (int r4 = 0; r4 < 4; ++r4) {
        int id = id0 + 4 * lg + r4;
        out[8000 + (size_t)id * GHQ + j] = hprev[r4];
        pv[r4] = hprev[r4] * wo;
    }
#pragma unroll
    for (int s = 1; s <= 8; s <<= 1)
#pragma unroll
        for (int r4 = 0; r4 < 4; ++r4)
            pv[r4] += __shfl_xor(pv[r4], s);
    if (lr == 0) {
#pragma unroll
        for (int r4 = 0; r4 < 4; ++r4)
            pred_s[w][4 * lg + r4] = pv[r4];
    }
    __syncthreads();
    if (tid < 16) {
        float s = pred_s[0][tid] + pred_s[1][tid] + pred_s[2][tid] + pred_s[3][tid] + bout[0];
        out[id0 + tid] = s;
    }
}

// -------------------- attention mean over batch (f16 in) ---------------------
__global__ void k_attn(const _Float16* __restrict__ alpha, float* __restrict__ out) {
    int gid = blockIdx.x * blockDim.x + threadIdx.x;   // t*EQ + e
    if (gid >= TQ * EQ) return;
    int tt = gid / EQ, e = gid % EQ;
    float a0 = 0.f, a1 = 0.f, a2 = 0.f, a3 = 0.f;
#pragma unroll
    for (int b = 0; b < BQ; ++b) {
        half4v v = *(const half4v*)&alpha[(((size_t)b * TQ + tt) * EQ + e) * HQ];
        a0 += (float)v[0]; a1 += (float)v[1]; a2 += (float)v[2]; a3 += (float)v[3];
    }
    float4 r = {a0 * 0.25f, a1 * 0.25f, a2 * 0.25f, a3 * 0.25f};
    *(float4*)&out[ATTN_OFF + (size_t)gid * HQ] = r;
}

extern "C" void kernel_launch(void* const* d_in, const int* in_sizes, int n_in,
                              void* d_out, int out_size, void* d_ws, size_t ws_size,
                              hipStream_t stream) {
    const float* nodef = (const float*)d_in[0];
    const float* edgef = (const float*)d_in[1];
    const float* Wn    = (const float*)d_in[2];
    const float* We    = (const float*)d_in[3];
    const float* att   = (const float*)d_in[4];
    const float* gamma = (const float*)d_in[5];
    const float* beta  = (const float*)d_in[6];
    const float* Wih   = (const float*)d_in[7];
    const float* Whh   = (const float*)d_in[8];
    const float* bih   = (const float*)d_in[9];
    const float* bhh   = (const float*)d_in[10];
    const float* Wout  = (const float*)d_in[11];
    const float* bout  = (const float*)d_in[12];
    const int*   ei    = (const int*)d_in[13];

    char* ws = (char*)d_ws;
    size_t o = 0;
    int*  count  = (int*)(ws + o);  o += 2048 * 4;
    int*  offs   = (int*)(ws + o);  o += 2048 * 4;
    int*  cursor = (int*)(ws + o);  o += 2048 * 4;
    int2* csr2   = (int2*)(ws + o); o += (size_t)EQ * 8;
    float* sd      = (float*)(ws + o); o += (size_t)NGQ * NQ * HQ * 4;
    float* ss      = (float*)(ws + o); o += (size_t)NGQ * NQ * HQ * 4;
    _Float16* hprojH   = (_Float16*)(ws + o); o += (size_t)NGQ * NQ * GQ * 2;
    _Float16* alphaH   = (_Float16*)(ws + o); o += (size_t)NGQ * EQ * HQ * 2;
    _Float16* spatialH = (_Float16*)(ws + o); o += (size_t)NGQ * NQ * GQ * 2;

    hipMemsetAsync(count, 0, NQ * sizeof(int), stream);
    k_count  <<<(EQ + 255) / 256, 256, 0, stream>>>(ei, count);
    k_scan   <<<1, 1024, 0, stream>>>(count, offs, cursor);
    k_scatter<<<(EQ + 255) / 256, 256, 0, stream>>>(ei, cursor, csr2);

    k_nodeproj<<<(NGQ * NQ) / 256, 256, 0, stream>>>(nodef, Wn, att, hprojH, sd, ss);
    k_fused   <<<(NGQ * NQ) / 4, 256, 0, stream>>>(edgef, We, att, offs, csr2,
                                                   sd, ss, hprojH, gamma, beta,
                                                   alphaH, spatialH);
    k_gru     <<<(BQ * NQ) / 16, 256, 0, stream>>>(spatialH, Wih, Whh, bih, bhh,
                                                   Wout, bout, (float*)d_out);
    k_attn    <<<(TQ * EQ + 255) / 256, 256, 0, stream>>>(alphaH, (float*)d_out);
}